// Round 4
// baseline (241.430 us; speedup 1.0000x reference)
//
#include <hip/hip_runtime.h>

// out[b, t, c*CTX + i] = (t < round(T*lengths[b]) && 0 <= t+i-LEFT < T)
//                          ? x[b, t+i-LEFT, c] : 0
// x: [32, 2000, 80] fp32; out: [32, 2000, 880] fp32 (225 MB, write-bound).
#define BB    32
#define TT    2000
#define CC    80
#define CTX   11
#define LEFTP 5

#define TL    20                 // time steps per block -> 3200 blocks
#define NROWS (TL + 2 * LEFTP)   // 30 staged x-rows
#define S     84                 // LDS row stride (words): 336 B, 16B-aligned; ~2-way banks (free)
#define ROWQ  220                // float4 per output time step (880/4)
#define NTILE (TT / TL)          // 100 tiles per batch

// native clang vector type — required by __builtin_nontemporal_store
typedef float fvec4 __attribute__((ext_vector_type(4)));

__global__ __launch_bounds__(256) void context_window_kernel(
    const float* __restrict__ x,
    const float* __restrict__ lengths,
    float* __restrict__ out)
{
    __shared__ float lds[NROWS * S];   // 10.1 KB -> LDS never the occupancy cap

    const int tile = blockIdx.x % NTILE;
    const int b    = blockIdx.x / NTILE;
    const int t0   = tile * TL;
    const int tid  = threadIdx.x;

    // len_abs = round(T * lengths[b]), ties-to-even (matches jnp.round)
    const int len = __float2int_rn((float)TT * lengths[b]);

    fvec4* outq = (fvec4*)out + ((size_t)b * TT + t0) * ROWQ;

    // ---- fast path: entire tile masked -> coalesced nontemporal zero fill ----
    if (t0 >= len) {
        const fvec4 z = (fvec4)0.f;
        for (int o = tid; o < TL * ROWQ; o += 256)
            __builtin_nontemporal_store(z, &outq[o]);
        return;
    }

    // ---- stage x rows [t0-5, t0+TL+5) into LDS (contiguous, coalesced) ----
    // 30 rows x 20 float4 = 600 float4
    const fvec4* xb4 = (const fvec4*)(x + (size_t)b * TT * CC);
    for (int idx = tid; idx < NROWS * (CC / 4); idx += 256) {
        int r    = idx / (CC / 4);
        int c4   = idx - r * (CC / 4);
        int trow = t0 - LEFTP + r;
        fvec4 v = (fvec4)0.f;
        if ((unsigned)trow < (unsigned)TT) v = xb4[trow * (CC / 4) + c4];
        *(fvec4*)&lds[r * S + c4 * 4] = v;   // 16B-aligned (S*4 = 336)
    }
    __syncthreads();

    // ---- compute: thread owns one float4 column q; tl unrolled x4 so 16 LDS
    //      reads issue back-to-back (one lgkm drain per 4 stores) ----
    if (tid < ROWQ) {
        int caddr[4];
#pragma unroll
        for (int j = 0; j < 4; ++j) {
            int k = 4 * tid + j;
            int c = k / CTX;
            int i = k - c * CTX;
            caddr[j] = i * S + c;
        }
        fvec4* op = outq + tid;
#pragma unroll
        for (int t4 = 0; t4 < TL; t4 += 4) {
            fvec4 v[4];
#pragma unroll
            for (int u = 0; u < 4; ++u) {
                const float* lp = &lds[(t4 + u) * S];
                v[u].x = lp[caddr[0]];
                v[u].y = lp[caddr[1]];
                v[u].z = lp[caddr[2]];
                v[u].w = lp[caddr[3]];
            }
#pragma unroll
            for (int u = 0; u < 4; ++u) {
                fvec4 w = (t0 + t4 + u < len) ? v[u] : (fvec4)0.f;
                __builtin_nontemporal_store(w, &op[(t4 + u) * ROWQ]);
            }
        }
    }
}

extern "C" void kernel_launch(void* const* d_in, const int* in_sizes, int n_in,
                              void* d_out, int out_size, void* d_ws, size_t ws_size,
                              hipStream_t stream) {
    const float* x       = (const float*)d_in[0];
    const float* lengths = (const float*)d_in[1];
    float* out           = (float*)d_out;

    const int grid = BB * NTILE;   // 32 * 100 = 3200 blocks
    context_window_kernel<<<grid, 256, 0, stream>>>(x, lengths, out);
}

// Round 5
// 232.660 us; speedup vs baseline: 1.0377x; 1.0377x over previous
//
#include <hip/hip_runtime.h>

// out[b, t, c*CTX + i] = (t < round(T*lengths[b]) && 0 <= t+i-LEFT < T)
//                          ? x[b, t+i-LEFT, c] : 0
// x: [32, 2000, 80] fp32; out: [32, 2000, 880] fp32 (225 MB, write-bound).
// Kernel floor ~36 us (225 MB out + 26 MB x @ 6.3 TB/s); harness adds ~190 us
// of poison/restore per timed replay (880 MB fill alone = 141 us in profile).
#define BB    32
#define TT    2000
#define CC    80
#define CTX   11
#define LEFTP 5

#define TL    40                 // time steps per block -> 1600 blocks (R2 best)
#define NROWS (TL + 2 * LEFTP)   // 50 staged x-rows
#define S     84                 // LDS row stride (words): 336 B, 16B-aligned; ~2-way banks (free)
#define ROWQ  220                // float4 per output time step (880/4)
#define NTILE (TT / TL)          // 50 tiles per batch
#define QPT   (TL * ROWQ)        // 8800 float4 per tile

typedef float fvec4 __attribute__((ext_vector_type(4)));

__global__ __launch_bounds__(256) void context_window_kernel(
    const float* __restrict__ x,
    const float* __restrict__ lengths,
    float* __restrict__ out)
{
    __shared__ float lds[NROWS * S];   // 16.8 KB
    __shared__ int   lut[ROWQ * 4];    // 3.5 KB: per-q gather offsets (int4)

    const int tile = blockIdx.x % NTILE;
    const int b    = blockIdx.x / NTILE;
    const int t0   = tile * TL;
    const int tid  = threadIdx.x;

    // len_abs = round(T * lengths[b]), ties-to-even (matches jnp.round)
    const int len = __float2int_rn((float)TT * lengths[b]);

    fvec4* outq = (fvec4*)out + ((size_t)b * TT + t0) * ROWQ;

    // ---- fast path: entire tile masked -> coalesced zero fill, all lanes ----
    if (t0 >= len) {
        const fvec4 z = (fvec4)0.f;
        for (int f = tid; f < QPT; f += 256)
            outq[f] = z;
        return;
    }

    // ---- stage x rows [t0-5, t0+TL+5) into LDS (contiguous, coalesced) ----
    const fvec4* xb4 = (const fvec4*)(x + (size_t)b * TT * CC);
    for (int idx = tid; idx < NROWS * (CC / 4); idx += 256) {
        int r    = idx / (CC / 4);
        int c4   = idx - r * (CC / 4);
        int trow = t0 - LEFTP + r;
        fvec4 v = (fvec4)0.f;
        if ((unsigned)trow < (unsigned)TT) v = xb4[trow * (CC / 4) + c4];
        *(fvec4*)&lds[r * S + c4 * 4] = v;   // 16B-aligned (S*4 = 336)
    }
    // ---- build gather-offset LUT (overlaps staging; same barrier) ----
    if (tid < ROWQ) {
        int o[4];
#pragma unroll
        for (int j = 0; j < 4; ++j) {
            int k = 4 * tid + j;
            int c = k / CTX;
            int i = k - c * CTX;
            o[j] = i * S + c;
        }
        *(int4*)&lut[tid * 4] = make_int4(o[0], o[1], o[2], o[3]);
    }
    __syncthreads();

    // ---- compute: flattened grid-stride over the tile -> all 256 lanes
    //      store a float4 every iteration (vs 220/256 previously) ----
    for (int f = tid; f < QPT; f += 256) {
        unsigned t = (unsigned)f / 220u;        // compiler magic-mul
        unsigned q = (unsigned)f - t * 220u;
        int4 o = *(const int4*)&lut[q * 4];     // ds_read_b128
        const float* lp = &lds[t * S];
        fvec4 v;
        v.x = lp[o.x];
        v.y = lp[o.y];
        v.z = lp[o.z];
        v.w = lp[o.w];
        if ((int)(t0 + t) >= len) v = (fvec4)0.f;
        outq[f] = v;
    }
}

extern "C" void kernel_launch(void* const* d_in, const int* in_sizes, int n_in,
                              void* d_out, int out_size, void* d_ws, size_t ws_size,
                              hipStream_t stream) {
    const float* x       = (const float*)d_in[0];
    const float* lengths = (const float*)d_in[1];
    float* out           = (float*)d_out;

    const int grid = BB * NTILE;   // 32 * 50 = 1600 blocks
    context_window_kernel<<<grid, 256, 0, stream>>>(x, lengths, out);
}